// Round 3
// baseline (74.314 us; speedup 1.0000x reference)
//
#include <hip/hip_runtime.h>

// Problem: inter[b,u,i,d] = user[b,u,d]*img[b,i,d]; out_user = sum over i,
// out_img = sum over u.
//   user: [B=32, U=128, D=256] fp32,  img: [B=32, I=256, D=256] fp32
//   out = concat(out_user [B,U,D], out_img [B,I,D]) flat fp32
//
// Single fused kernel, NO workspace: each block recomputes the per-batch
// sum it needs from the (L2/LLC-hot) inputs, then scales its output chunk.
// Removes one graph node + the reduce->multiply serialization + ws traffic.
#define B 32
#define U 128
#define I 256
#define D 256
#define D4 (D / 4)  // 64 float4 per row

__global__ void __launch_bounds__(256) fused_interaction_kernel(
    const float* __restrict__ user,
    const float* __restrict__ img,
    float* __restrict__ out) {
  __shared__ float4 part[4][64];
  const int tid = threadIdx.x;
  const int rg  = tid >> 6;   // wave id 0..3
  const int d4  = tid & 63;   // float4 column 0..63
  const int blk = blockIdx.x;

  const float4* u4 = (const float4*)user;
  const float4* i4 = (const float4*)img;
  float4* o4 = (float4*)out;
  constexpr size_t NU4 = (size_t)B * U * D4;  // float4 offset of out_img

  if (blk < 128) {
    // ---- out_user block: b = blk/4, 32-row chunk c = blk%4 ----
    const int b = blk >> 2, c = blk & 3;
    const float4* ib = i4 + (size_t)b * I * D4;

    // Phase 1: img_sum[b][d] — each thread sums 64 rows (i = rg + 4*t)
    float4 acc = make_float4(0.f, 0.f, 0.f, 0.f);
    #pragma unroll 8
    for (int t = 0; t < 64; ++t) {
      const float4 v = ib[(size_t)(rg + 4 * t) * D4 + d4];
      acc.x += v.x; acc.y += v.y; acc.z += v.z; acc.w += v.w;
    }
    part[rg][d4] = acc;
    __syncthreads();
    const float4 s0 = part[0][d4], s1 = part[1][d4];
    const float4 s2 = part[2][d4], s3 = part[3][d4];
    const float4 s = make_float4(s0.x + s1.x + s2.x + s3.x,
                                 s0.y + s1.y + s2.y + s3.y,
                                 s0.z + s1.z + s2.z + s3.z,
                                 s0.w + s1.w + s2.w + s3.w);

    // Phase 2: scale user rows c*32 .. c*32+31 (wave rg: rows rg*8..rg*8+7)
    const float4* ub = u4 + (size_t)b * U * D4;
    float4* ob = o4 + (size_t)b * U * D4;
    #pragma unroll
    for (int it = 0; it < 8; ++it) {
      const size_t r = (size_t)(c * 32 + rg * 8 + it);
      const float4 v = ub[r * D4 + d4];
      ob[r * D4 + d4] = make_float4(v.x * s.x, v.y * s.y, v.z * s.z, v.w * s.w);
    }
  } else {
    // ---- out_img block: b = (blk-128)/8, 32-row chunk c = (blk-128)%8 ----
    const int k = blk - 128;
    const int b = k >> 3, c = k & 7;
    const float4* ub = u4 + (size_t)b * U * D4;

    // Phase 1: user_sum[b][d] — each thread sums 32 rows (u = rg + 4*t)
    float4 acc = make_float4(0.f, 0.f, 0.f, 0.f);
    #pragma unroll 8
    for (int t = 0; t < 32; ++t) {
      const float4 v = ub[(size_t)(rg + 4 * t) * D4 + d4];
      acc.x += v.x; acc.y += v.y; acc.z += v.z; acc.w += v.w;
    }
    part[rg][d4] = acc;
    __syncthreads();
    const float4 s0 = part[0][d4], s1 = part[1][d4];
    const float4 s2 = part[2][d4], s3 = part[3][d4];
    const float4 s = make_float4(s0.x + s1.x + s2.x + s3.x,
                                 s0.y + s1.y + s2.y + s3.y,
                                 s0.z + s1.z + s2.z + s3.z,
                                 s0.w + s1.w + s2.w + s3.w);

    // Phase 2: scale img rows c*32 .. c*32+31
    const float4* ib = i4 + (size_t)b * I * D4;
    float4* ob = o4 + NU4 + (size_t)b * I * D4;
    #pragma unroll
    for (int it = 0; it < 8; ++it) {
      const size_t r = (size_t)(c * 32 + rg * 8 + it);
      const float4 v = ib[r * D4 + d4];
      ob[r * D4 + d4] = make_float4(v.x * s.x, v.y * s.y, v.z * s.z, v.w * s.w);
    }
  }
}

extern "C" void kernel_launch(void* const* d_in, const int* in_sizes, int n_in,
                              void* d_out, int out_size, void* d_ws, size_t ws_size,
                              hipStream_t stream) {
  const float* user = (const float*)d_in[0];
  const float* img  = (const float*)d_in[1];
  float* out = (float*)d_out;
  (void)d_ws; (void)ws_size;

  fused_interaction_kernel<<<dim3(384), dim3(256), 0, stream>>>(user, img, out);
}